// Round 4
// baseline (118.288 us; speedup 1.0000x reference)
//
#include <hip/hip_runtime.h>

#define NSEQ   24
#define NBOX   196
#define NCTX   196
#define MAXLEN 6
#define EPSV   1e-6f
#define BS     32

#define TILES      49    // i-tiles per batch: 4 i per block, 49*4 = 196 exact
#define K1_THREADS 512
#define NB4        (NBOX / 4)   // 49 float4 per row

// ------------------------------------------------- per-step: compute add_raw
// add_raw[b,i] = kcls_i * sum_j sum_c cae[j][ctx[b,i,c]] * spo[b,e_j,i,c] * rm[b,i,c]
// Wave pair (2k,2k+1) shares i = tile*4+k; even wave does children 0,2,4..,
// odd wave does 1,3,5..; partials combined via LDS.
__global__ __launch_bounds__(K1_THREADS) void step_compute(
    const float* __restrict__ src,      // ent (step 0) or ea (current state)
    float*       __restrict__ ea_copy,  // ea; written only when step==0
    const float* __restrict__ spo,      // [BS, NSEQ, NBOX, NCTX]
    const int*   __restrict__ ctx,      // [BS, NBOX, NCTX]
    const int*   __restrict__ roi_cls,  // [BS, NBOX]
    const float* __restrict__ rm,       // [BS, NBOX, NCTX]
    const int*   __restrict__ trav,     // [BS, MAXLEN]
    const int*   __restrict__ adj,      // [BS, NSEQ, NSEQ]
    float*       __restrict__ add_raw,  // ws: [BS, NBOX]
    int step)
{
    const int b    = blockIdx.x / TILES;
    const int tile = blockIdx.x % TILES;
    const int tid  = threadIdx.x;

    __shared__ __align__(16) float cae[NSEQ][NBOX]; // child rows * kcls, compacted
    __shared__ int   s_childE[NSEQ + 6];            // +6 pad: stride-2 walk, 3-deep prefetch
    __shared__ int   s_childJ[NSEQ];
    __shared__ float s_part[8];
    __shared__ int   s_nch;

    // fused ent -> ea copy on step 0 (no kernel in this dispatch reads ea)
    if (step == 0) {
        const int total4 = BS * NSEQ * NBOX / 4;
        int idx = blockIdx.x * K1_THREADS + tid;
        if (idx < total4)
            ((float4*)ea_copy)[idx] = ((const float4*)src)[idx];
    }

    const int p = trav[b * MAXLEN + step];
    if (tid == 0) {
        int n = 0;
        if (p >= 0) {
            const int* arow = adj + ((size_t)b * NSEQ + p) * NSEQ;
            for (int j = 0; j < NSEQ; ++j) {
                int e = arow[j];
                if (e >= 0) { s_childJ[n] = j; s_childE[n] = e; ++n; }
            }
        }
        int c0 = (n > 0) ? s_childE[0] : 0;
        #pragma unroll
        for (int q = 0; q < 6; ++q) s_childE[n + q] = c0;  // prefetch pad
        s_nch = n;
    }
    __syncthreads();
    const int nch = s_nch;
    if (nch == 0) return;  // uniform per block; finalize kernel also skips

    // stage child attention rows * kcls into LDS (float4)
    {
        const int items = nch * NB4;
        const int4* roi4 = (const int4*)(roi_cls + b * NBOX);
        for (int t = tid; t < items; t += K1_THREADS) {
            int n = t / NB4;
            int q = t - n * NB4;
            float4 e4 = ((const float4*)(src + ((size_t)b * NSEQ + s_childJ[n]) * NBOX))[q];
            int4   r4 = roi4[q];
            float4 v;
            v.x = (r4.x != -1) ? e4.x : 0.0f;
            v.y = (r4.y != -1) ? e4.y : 0.0f;
            v.z = (r4.z != -1) ? e4.z : 0.0f;
            v.w = (r4.w != -1) ? e4.w : 0.0f;
            ((float4*)&cae[n][0])[q] = v;
        }
    }
    __syncthreads();

    const int wave = tid >> 6;
    const int lane = tid & 63;
    const int i    = tile * 4 + (wave >> 1);   // two waves per i
    const int half = wave & 1;                 // child-parity this wave owns

    float acc = 0.0f;
    if (lane < NB4) {
        const size_t bi = (size_t)b * NBOX + i;
        const int4   idx4 = ((const int4*)  (ctx + bi * NCTX))[lane];
        const float4 m4   = ((const float4*)(rm  + bi * NCTX))[lane];
        const float* sb = spo + ((size_t)b * NSEQ * NBOX + i) * NCTX;
        const size_t stride = (size_t)NBOX * NCTX;

        float4 a4 = make_float4(0.f, 0.f, 0.f, 0.f);
        float4 s0 = ((const float4*)(sb + (size_t)s_childE[half    ] * stride))[lane];
        float4 s1 = ((const float4*)(sb + (size_t)s_childE[half + 2] * stride))[lane];
        float4 s2 = ((const float4*)(sb + (size_t)s_childE[half + 4] * stride))[lane];
        for (int n = half; n < nch; n += 2) {
            float4 nx = ((const float4*)(sb + (size_t)s_childE[n + 6] * stride))[lane];
            a4.x = fmaf(m4.x * cae[n][idx4.x], s0.x, a4.x);
            a4.y = fmaf(m4.y * cae[n][idx4.y], s0.y, a4.y);
            a4.z = fmaf(m4.z * cae[n][idx4.z], s0.z, a4.z);
            a4.w = fmaf(m4.w * cae[n][idx4.w], s0.w, a4.w);
            s0 = s1; s1 = s2; s2 = nx;
        }
        acc = (a4.x + a4.y) + (a4.z + a4.w);
    }
    #pragma unroll
    for (int off = 32; off >= 1; off >>= 1)
        acc += __shfl_down(acc, off, 64);
    if (lane == 0) s_part[wave] = acc;
    __syncthreads();

    if (tid < 4) {
        const int i2 = tile * 4 + tid;
        float sum = s_part[2 * tid] + s_part[2 * tid + 1];
        float kci = (roi_cls[b * NBOX + i2] != -1) ? 1.0f : 0.0f;
        add_raw[b * NBOX + i2] = kci * sum;
    }
}

// ------------------------------------------------- per-step: finalize + write
__global__ __launch_bounds__(256) void step_finalize(
    float*       __restrict__ ea,       // [BS, NSEQ, NBOX] in/out
    const float* __restrict__ add_raw,  // ws: [BS, NBOX]
    const float* __restrict__ wc,       // [BS, NSEQ, NBOX]
    const int*   __restrict__ roi_cls,  // [BS, NBOX]
    const int*   __restrict__ trav,     // [BS, MAXLEN]
    const int*   __restrict__ adj,      // [BS, NSEQ, NSEQ]
    int step)
{
    const int b   = blockIdx.x;
    const int tid = threadIdx.x;
    const int p   = trav[b * MAXLEN + step];

    int nch = 0;
    if (p >= 0) {
        const int* arow = adj + ((size_t)b * NSEQ + p) * NSEQ;
        for (int j = 0; j < NSEQ; ++j) nch += (arow[j] >= 0) ? 1 : 0;
    }
    if (p < 0 || nch == 0) return;  // row stays unchanged

    float upd = 0.0f, a = 0.0f;
    if (tid < NBOX) {
        const float sub = ea[((size_t)b * NSEQ + p) * NBOX + tid];
        const float w   = wc[((size_t)b * NSEQ + p) * NBOX + tid];
        upd = sub + (add_raw[b * NBOX + tid] + (float)nch * EPSV) * w;
        a = fabsf(upd);
    }
    #pragma unroll
    for (int off = 32; off >= 1; off >>= 1)
        a = fmaxf(a, __shfl_down(a, off, 64));
    __shared__ float wmax[4];
    if ((tid & 63) == 0) wmax[tid >> 6] = a;
    __syncthreads();
    float norm = fmaxf(fmaxf(wmax[0], wmax[1]), fmaxf(wmax[2], wmax[3]));
    norm = (norm <= 1.0f) ? 1.0f : norm;
    if (tid < NBOX) {
        float val = upd / norm;
        if (roi_cls[b * NBOX + tid] == -1) val = -1.0f;
        ea[((size_t)b * NSEQ + p) * NBOX + tid] = val;
    }
}

extern "C" void kernel_launch(void* const* d_in, const int* in_sizes, int n_in,
                              void* d_out, int out_size, void* d_ws, size_t ws_size,
                              hipStream_t stream) {
    const int*   trav = (const int*)  d_in[0];
    const int*   adj  = (const int*)  d_in[1];
    const float* ent  = (const float*)d_in[2];
    const float* spo  = (const float*)d_in[3];
    const int*   ctx  = (const int*)  d_in[4];
    const int*   roi  = (const int*)  d_in[5];
    const float* rm   = (const float*)d_in[6];
    const float* wc   = (const float*)d_in[7];

    float* ea      = (float*)d_out;
    float* add_raw = (float*)d_ws;   // BS*NBOX floats (~25 KB)

    for (int t = 0; t < MAXLEN; ++t) {
        step_compute<<<BS * TILES, K1_THREADS, 0, stream>>>(
            t == 0 ? ent : ea, ea, spo, ctx, roi, rm, trav, adj, add_raw, t);
        step_finalize<<<BS, 256, 0, stream>>>(
            ea, add_raw, wc, roi, trav, adj, t);
    }
}

// Round 5
// 101.225 us; speedup vs baseline: 1.1686x; 1.1686x over previous
//
#include <hip/hip_runtime.h>

#define NSEQ   24
#define NBOX   196
#define NCTX   196
#define MAXLEN 6
#define EPSV   1e-6f
#define BS     32

#define TILES      25    // i-tiles per batch; 8 waves/block, 1 i per wave
#define K1T        512
#define NB4        49    // float4 chunks per 196-row
#define ROWP       200   // padded cae row: 196 data + 4 zeros (sentinel idx 196)

// ws layout: midx[BS][NBOX][NCTX] ints, then araw[BS][NBOX] floats
#define MIDX_ELEMS ((size_t)BS * NBOX * NCTX)

// add_raw[b,i] = kcls_i * sum_n sum_c cae[n][midx[b,i,c]] * spo[b,e_n,i,c]
// where midx = rm ? ctx : 196 and cae[n][196..199] = 0 (rm folded as sentinel).
// mode: 0 = compute midx from ctx+rm each step (fallback, no store)
//       1 = compute and STORE midx (step 0)
//       2 = load midx from ws (steps 1..5)
__global__ __launch_bounds__(K1T, 6) void step_compute(
    const float* __restrict__ src,      // ent (step 0) or ea (current state)
    float*       __restrict__ ea_copy,  // ea; written only when step==0
    const float* __restrict__ spo,      // [BS, NSEQ, NBOX, NCTX]
    const int*   __restrict__ ctx,      // [BS, NBOX, NCTX]
    const int*   __restrict__ roi_cls,  // [BS, NBOX]
    const float* __restrict__ rm,       // [BS, NBOX, NCTX]
    const int*   __restrict__ trav,     // [BS, MAXLEN]
    const int*   __restrict__ adj,      // [BS, NSEQ, NSEQ]
    int*         __restrict__ midx,     // ws
    float*       __restrict__ araw,     // ws
    int step, int mode)
{
    const int b    = blockIdx.x / TILES;
    const int tile = blockIdx.x % TILES;
    const int tid  = threadIdx.x;
    const int wave = tid >> 6;
    const int lane = tid & 63;

    __shared__ __align__(16) float cae[NSEQ][ROWP];

    // ---- fused ent -> ea copy (step 0; nothing reads ea this dispatch)
    if (step == 0) {
        const int total4 = BS * NSEQ * NBOX / 4;
        int idx = blockIdx.x * K1T + tid;
        if (idx < total4) ((float4*)ea_copy)[idx] = ((const float4*)src)[idx];
    }

    // ---- wave-parallel adjacency parse (every wave, registers only)
    const int p = trav[b * MAXLEN + step];
    int e = -1;
    if (p >= 0 && lane < NSEQ)
        e = adj[((size_t)b * NSEQ + p) * NSEQ + lane];
    const unsigned long long mask = __ballot(e >= 0);
    const int nch = __popcll(mask);

    int ec = 0, jc = 0;   // lane n holds e/j of child n (lanes >= nch: child 0)
    if (nch > 0) {
        unsigned long long m = mask;
        const int lim = (lane < NSEQ) ? lane : NSEQ;
        for (int k = 0; k < lim; ++k) m &= (m - 1);
        const int j0 = __ffsll(mask) - 1;
        const int jn = m ? (__ffsll(m) - 1) : j0;
        jc = (lane < nch) ? jn : j0;
        ec = __shfl(e, jc);
    }

    // ---- stage child rows * kcls into LDS (wave w stages children w, w+8, w+16)
    if (nch > 0) {
        for (int n = wave; n < nch; n += 8) {
            const int j = __shfl(jc, n);
            if (lane < 50) {
                float4 v = make_float4(0.f, 0.f, 0.f, 0.f);
                if (lane < NB4) {
                    float4 e4 = ((const float4*)(src + ((size_t)b * NSEQ + j) * NBOX))[lane];
                    int4   r4 = ((const int4*)(roi_cls + b * NBOX))[lane];
                    v.x = (r4.x != -1) ? e4.x : 0.f;
                    v.y = (r4.y != -1) ? e4.y : 0.f;
                    v.z = (r4.z != -1) ? e4.z : 0.f;
                    v.w = (r4.w != -1) ? e4.w : 0.f;
                }
                ((float4*)&cae[n][0])[lane] = v;   // lane 49 writes the zero pad
            }
        }
        __syncthreads();
    }

    // ---- one i per wave
    const int i = tile * 8 + wave;
    if (i >= NBOX) return;

    float acc = 0.f;
    if (lane < NB4) {
        const size_t bi = (size_t)b * NBOX + i;
        int4 mi;
        if (mode == 2) {
            mi = ((const int4*)(midx + bi * NCTX))[lane];
        } else {
            const int4   ix = ((const int4*)  (ctx + bi * NCTX))[lane];
            const float4 m4 = ((const float4*)(rm  + bi * NCTX))[lane];
            mi.x = (m4.x != 0.f) ? ix.x : NBOX;
            mi.y = (m4.y != 0.f) ? ix.y : NBOX;
            mi.z = (m4.z != 0.f) ? ix.z : NBOX;
            mi.w = (m4.w != 0.f) ? ix.w : NBOX;
            if (mode == 1) ((int4*)(midx + bi * NCTX))[lane] = mi;
        }

        if (nch > 0) {
            const float* sb = spo + ((size_t)b * NSEQ * NBOX + i) * NCTX;
            const size_t st = (size_t)NBOX * NCTX;
            const int e0 = __shfl(ec, 0), e1 = __shfl(ec, 1), e2 = __shfl(ec, 2);
            float4 s0 = ((const float4*)(sb + (size_t)e0 * st))[lane];
            float4 s1 = ((const float4*)(sb + (size_t)e1 * st))[lane];
            float4 s2 = ((const float4*)(sb + (size_t)e2 * st))[lane];
            float4 a4 = make_float4(0.f, 0.f, 0.f, 0.f);
            for (int n = 0; n < nch; ++n) {
                const int ep = __shfl(ec, n + 3);   // lanes >= nch hold child-0 e (safe pad)
                float4 nx = ((const float4*)(sb + (size_t)ep * st))[lane];
                a4.x = fmaf(cae[n][mi.x], s0.x, a4.x);
                a4.y = fmaf(cae[n][mi.y], s0.y, a4.y);
                a4.z = fmaf(cae[n][mi.z], s0.z, a4.z);
                a4.w = fmaf(cae[n][mi.w], s0.w, a4.w);
                s0 = s1; s1 = s2; s2 = nx;
            }
            acc = (a4.x + a4.y) + (a4.z + a4.w);
        }
    }

    if (nch > 0) {
        #pragma unroll
        for (int off = 32; off >= 1; off >>= 1)
            acc += __shfl_down(acc, off, 64);
        if (lane == 0) {
            float kci = (roi_cls[b * NBOX + i] != -1) ? 1.0f : 0.0f;
            araw[b * NBOX + i] = kci * acc;
        }
    }
}

// ------------------------------------------------- per-step: finalize + write
__global__ __launch_bounds__(256) void step_finalize(
    float*       __restrict__ ea,       // [BS, NSEQ, NBOX] in/out
    const float* __restrict__ araw,     // ws: [BS, NBOX]
    const float* __restrict__ wc,       // [BS, NSEQ, NBOX]
    const int*   __restrict__ roi_cls,  // [BS, NBOX]
    const int*   __restrict__ trav,     // [BS, MAXLEN]
    const int*   __restrict__ adj,      // [BS, NSEQ, NSEQ]
    int step)
{
    const int b   = blockIdx.x;
    const int tid = threadIdx.x;
    const int p   = trav[b * MAXLEN + step];

    int nch = 0;
    if (p >= 0) {
        const int* arow = adj + ((size_t)b * NSEQ + p) * NSEQ;
        for (int j = 0; j < NSEQ; ++j) nch += (arow[j] >= 0) ? 1 : 0;
    }
    if (p < 0 || nch == 0) return;  // row stays unchanged

    float upd = 0.0f, a = 0.0f;
    if (tid < NBOX) {
        const float sub = ea[((size_t)b * NSEQ + p) * NBOX + tid];
        const float w   = wc[((size_t)b * NSEQ + p) * NBOX + tid];
        upd = sub + (araw[b * NBOX + tid] + (float)nch * EPSV) * w;
        a = fabsf(upd);
    }
    #pragma unroll
    for (int off = 32; off >= 1; off >>= 1)
        a = fmaxf(a, __shfl_down(a, off, 64));
    __shared__ float wmax[4];
    if ((tid & 63) == 0) wmax[tid >> 6] = a;
    __syncthreads();
    float norm = fmaxf(fmaxf(wmax[0], wmax[1]), fmaxf(wmax[2], wmax[3]));
    norm = (norm <= 1.0f) ? 1.0f : norm;
    if (tid < NBOX) {
        float val = upd / norm;
        if (roi_cls[b * NBOX + tid] == -1) val = -1.0f;
        ea[((size_t)b * NSEQ + p) * NBOX + tid] = val;
    }
}

extern "C" void kernel_launch(void* const* d_in, const int* in_sizes, int n_in,
                              void* d_out, int out_size, void* d_ws, size_t ws_size,
                              hipStream_t stream) {
    const int*   trav = (const int*)  d_in[0];
    const int*   adj  = (const int*)  d_in[1];
    const float* ent  = (const float*)d_in[2];
    const float* spo  = (const float*)d_in[3];
    const int*   ctx  = (const int*)  d_in[4];
    const int*   roi  = (const int*)  d_in[5];
    const float* rm   = (const float*)d_in[6];
    const float* wc   = (const float*)d_in[7];

    float* ea = (float*)d_out;

    const bool ws_ok = ws_size >= (MIDX_ELEMS + (size_t)BS * NBOX) * 4;
    int*   midx = (int*)d_ws;
    float* araw = ws_ok ? ((float*)d_ws + MIDX_ELEMS) : (float*)d_ws;

    for (int t = 0; t < MAXLEN; ++t) {
        const int mode = ws_ok ? (t == 0 ? 1 : 2) : 0;
        step_compute<<<BS * TILES, K1T, 0, stream>>>(
            t == 0 ? ent : ea, ea, spo, ctx, roi, rm, trav, adj,
            midx, araw, t, mode);
        step_finalize<<<BS, 256, 0, stream>>>(
            ea, araw, wc, roi, trav, adj, t);
    }
}